// Round 9
// baseline (462.435 us; speedup 1.0000x reference)
//
#include <hip/hip_runtime.h>
#include <hip/hip_bf16.h>

constexpr int N    = 8192;
constexpr int FIN  = 512;
constexpr int FOUT = 64;
constexpr int NSPLIT = 8;            // j-split across blocks -> 1024 blocks, co-resident
constexpr int JCHUNK = N / NSPLIT;   // 1024 j per block
constexpr int NSLICE = 4;            // internal slices per block
constexpr int JS     = JCHUNK / NSLICE;  // 256 j per LDS staging round
constexpr int LROW   = JS + 8;       // LDS B row pitch in bf16 (264 shorts)

typedef __attribute__((ext_vector_type(8))) short short8;
typedef __attribute__((ext_vector_type(4))) float f32x4;

union BF2U { unsigned int u; __hip_bfloat162 h; };

// ---------------------------------------------------------------------------
// Kernel 1: h = input @ W (fp32), fused epilogue:
//   E1=exp(s1), F1=exp(0.2 s1), E2=exp(s2), F2=exp(0.2 s2)  (exp-free k2)
//   + bf16 h^T write (B-operand feed for MFMA).   (unchanged from R7)
// ---------------------------------------------------------------------------
__global__ __launch_bounds__(256) void k1_proj(
    const float* __restrict__ input, const float* __restrict__ W,
    const float* __restrict__ a, __hip_bfloat16* __restrict__ hbT,
    float* __restrict__ E1, float* __restrict__ F1,
    float* __restrict__ E2, float* __restrict__ F2)
{
    __shared__ __hip_bfloat16 tile[8][64];
    const int tid  = threadIdx.x;
    const int col  = tid & 63;
    const int g    = tid >> 6;
    const int rbase = blockIdx.x * 8;

    float acc[2] = {0.f, 0.f};
    const float* in0 = input + (size_t)(rbase + g * 2) * FIN;

    for (int k = 0; k < FIN; k += 8) {
        float w[8];
        #pragma unroll
        for (int q = 0; q < 8; ++q) w[q] = W[(k + q) * FOUT + col];
        const float4 x0a = *(const float4*)(in0 + 0 * FIN + k);
        const float4 x0b = *(const float4*)(in0 + 0 * FIN + k + 4);
        const float4 x1a = *(const float4*)(in0 + 1 * FIN + k);
        const float4 x1b = *(const float4*)(in0 + 1 * FIN + k + 4);
        acc[0] = fmaf(x0a.w, w[3], fmaf(x0a.z, w[2], fmaf(x0a.y, w[1], fmaf(x0a.x, w[0], acc[0]))));
        acc[0] = fmaf(x0b.w, w[7], fmaf(x0b.z, w[6], fmaf(x0b.y, w[5], fmaf(x0b.x, w[4], acc[0]))));
        acc[1] = fmaf(x1a.w, w[3], fmaf(x1a.z, w[2], fmaf(x1a.y, w[1], fmaf(x1a.x, w[0], acc[1]))));
        acc[1] = fmaf(x1b.w, w[7], fmaf(x1b.z, w[6], fmaf(x1b.y, w[5], fmaf(x1b.x, w[4], acc[1]))));
    }

    const float a1c = a[col];
    const float a2c = a[FOUT + col];
    #pragma unroll
    for (int q = 0; q < 2; ++q) {
        float r1 = acc[q] * a1c;
        float r2 = acc[q] * a2c;
        #pragma unroll
        for (int off = 32; off >= 1; off >>= 1) {
            r1 += __shfl_xor(r1, off, 64);
            r2 += __shfl_xor(r2, off, 64);
        }
        if (col == 0) {
            const int i = rbase + g * 2 + q;
            E1[i] = __expf(r1);
            F1[i] = __expf(0.2f * r1);
            E2[i] = __expf(r2);
            F2[i] = __expf(0.2f * r2);
        }
        tile[g * 2 + q][col] = __float2bfloat16(acc[q]);
    }
    __syncthreads();

    if (tid < 128) {
        const int c = tid >> 1, part = tid & 1;
        unsigned short v[4];
        #pragma unroll
        for (int u = 0; u < 4; ++u) {
            __hip_bfloat16 hv = tile[part * 4 + u][c];
            v[u] = *reinterpret_cast<unsigned short*>(&hv);
        }
        *(ushort4*)((unsigned short*)hbT + (size_t)c * N + rbase + part * 4) =
            make_ushort4(v[0], v[1], v[2], v[3]);
    }
}

// ---------------------------------------------------------------------------
// Kernel 2: attention + PV via MFMA. R9 = R7 base + two surgical changes:
//  (1) slice-order rotation (slix+r)&3: concurrent blocks cover the full 32 KB
//      adj row pitch (channel aliasing fix without R8's restructure).
//  (2) adj register prefetch: wave owns rows w*16..+15; first 8 rows of slice
//      n+1 issued BEFORE slice n's compute (800+ cyc of MFMA hides HBM
//      latency), packed after the barrier. Waves pack/read only their own Ml
//      rows, so no extra sync. +32 VGPR only.
// grid (128 r-tiles, 8 s-chunks) = 1024 blocks, ~38 KB LDS, 4 blocks/CU.
// ---------------------------------------------------------------------------
__global__ __launch_bounds__(256, 4) void k2_attn(
    const int* __restrict__ adj,
    const float* __restrict__ E1, const float* __restrict__ F1,
    const float* __restrict__ E2, const float* __restrict__ F2,
    const unsigned short* __restrict__ hbT,
    float* __restrict__ pAcc, float* __restrict__ pZ)
{
    __shared__ unsigned short Bl[64 * LROW];   // 33.8 KB, padded rows
    __shared__ unsigned int   Ml[64 * 9];      // bitmask: 8 u32/row + 1 pad word
    __shared__ float          E2l[JS];         // 1 KB
    __shared__ float          F2l[JS];         // 1 KB

    const int r   = blockIdx.x;
    const int s   = blockIdx.y;
    const int tid = threadIdx.x;
    const int w     = tid >> 6;
    const int lane  = tid & 63;
    const int row16 = lane & 15;
    const int quad  = lane >> 4;

    const int iloc = w * 16 + row16;
    const int i    = r * 64 + iloc;
    const float E1i = E1[i];
    const float F1i = F1[i];

    short8 ones;
    #pragma unroll
    for (int q = 0; q < 8; ++q) ones[q] = (short)0x3F80;   // bf16 1.0

    f32x4 acc0 = {0.f, 0.f, 0.f, 0.f};
    f32x4 acc1 = {0.f, 0.f, 0.f, 0.f};
    f32x4 acc2 = {0.f, 0.f, 0.f, 0.f};
    f32x4 acc3 = {0.f, 0.f, 0.f, 0.f};
    f32x4 accz = {0.f, 0.f, 0.f, 0.f};

    unsigned char* Mlb = (unsigned char*)Ml;   // row pitch 36 bytes

    // prologue: prefetch first 8 rows of slice order[0]
    int4 pf[8];
    {
        const int jb0 = s * JCHUNK + ((0 + r) & (NSLICE - 1)) * JS;
        #pragma unroll
        for (int rr = 0; rr < 8; ++rr)
            pf[rr] = *(const int4*)(adj + (size_t)(r * 64 + w * 16 + rr) * N + jb0 + lane * 4);
    }

    #pragma unroll
    for (int slix = 0; slix < NSLICE; ++slix) {
        const int sl   = (slix + r) & (NSLICE - 1);   // rotated slice order
        const int jbeg = s * JCHUNK + sl * JS;

        // ---- pack prefetched rows (w*16 .. +7) into Ml ----
        #pragma unroll
        for (int rr = 0; rr < 8; ++rr) {
            const int rloc = w * 16 + rr;
            const int4 av = pf[rr];
            unsigned int nib =
                (av.x != 0 ? 1u : 0u) | (av.y != 0 ? 2u : 0u) |
                (av.z != 0 ? 4u : 0u) | (av.w != 0 ? 8u : 0u);
            const unsigned int other = __shfl_xor(nib, 1, 64);
            if (!(lane & 1))
                Mlb[rloc * 36 + (lane >> 1)] = (unsigned char)(nib | (other << 4));
        }
        // ---- load + pack remaining rows (w*16+8 .. +15) ----
        #pragma unroll
        for (int rr = 8; rr < 16; ++rr) {
            const int rloc = w * 16 + rr;
            const int4 av = *(const int4*)(adj + (size_t)(r * 64 + rloc) * N + jbeg + lane * 4);
            unsigned int nib =
                (av.x != 0 ? 1u : 0u) | (av.y != 0 ? 2u : 0u) |
                (av.z != 0 ? 4u : 0u) | (av.w != 0 ? 8u : 0u);
            const unsigned int other = __shfl_xor(nib, 1, 64);
            if (!(lane & 1))
                Mlb[rloc * 36 + (lane >> 1)] = (unsigned char)(nib | (other << 4));
        }

        // ---- stage B: 64 feature rows x 256 bf16 ----
        #pragma unroll
        for (int rr = 0; rr < 8; ++rr) {
            const int seg = rr * 256 + tid;        // [0, 2048) 16B-segments
            const int f = seg >> 5, o = seg & 31;
            const short8 v = *(const short8*)((const short*)hbT + (size_t)f * N + jbeg + o * 8);
            *(short8*)(&Bl[f * LROW + o * 8]) = v;
        }
        // ---- stage E2/F2 slices (JS == 256 == blockDim) ----
        E2l[tid] = E2[jbeg + tid];
        F2l[tid] = F2[jbeg + tid];
        __syncthreads();

        // ---- issue prefetch for next slice BEFORE compute (latency hiding) --
        if (slix + 1 < NSLICE) {
            const int jbn = s * JCHUNK + (((slix + 1) + r) & (NSLICE - 1)) * JS;
            #pragma unroll
            for (int rr = 0; rr < 8; ++rr)
                pf[rr] = *(const int4*)(adj + (size_t)(r * 64 + w * 16 + rr) * N + jbn + lane * 4);
        }

        #pragma unroll
        for (int it = 0; it < JS / 32; ++it) {     // 8 iterations
            const int jj = it * 32 + quad * 8;

            const unsigned int mword = Ml[iloc * 9 + it];
            const unsigned int mbyte = (mword >> (8 * quad)) & 0xffu;

            const float4 eA = *(const float4*)(&E2l[jj]);
            const float4 eB = *(const float4*)(&E2l[jj + 4]);
            const float4 fA = *(const float4*)(&F2l[jj]);
            const float4 fB = *(const float4*)(&F2l[jj + 4]);

            const short8 b0 = *(const short8*)(&Bl[(row16 +  0) * LROW + jj]);
            const short8 b1 = *(const short8*)(&Bl[(row16 + 16) * LROW + jj]);
            const short8 b2 = *(const short8*)(&Bl[(row16 + 32) * LROW + jj]);
            const short8 b3 = *(const short8*)(&Bl[(row16 + 48) * LROW + jj]);

            float e2v[8], f2v[8];
            e2v[0] = eA.x; e2v[1] = eA.y; e2v[2] = eA.z; e2v[3] = eA.w;
            e2v[4] = eB.x; e2v[5] = eB.y; e2v[6] = eB.z; e2v[7] = eB.w;
            f2v[0] = fA.x; f2v[1] = fA.y; f2v[2] = fA.z; f2v[3] = fA.w;
            f2v[4] = fB.x; f2v[5] = fB.y; f2v[6] = fB.z; f2v[7] = fB.w;

            float pv[8];
            #pragma unroll
            for (int j = 0; j < 8; ++j) {
                // exp(leakyrelu(s1+s2)) == max(E1*E2, F1*F2) exactly
                float p = fmaxf(E1i * e2v[j], F1i * f2v[j]);
                pv[j] = ((mbyte >> j) & 1u) ? p : 0.f;
            }

            short8 afrag;
            #pragma unroll
            for (int jp = 0; jp < 4; ++jp) {       // packed bf16 cvt (RNE)
                BF2U cv;
                cv.h = __float22bfloat162_rn(make_float2(pv[2 * jp], pv[2 * jp + 1]));
                afrag[2 * jp]     = (short)(cv.u & 0xffffu);
                afrag[2 * jp + 1] = (short)(cv.u >> 16);
            }

            acc0 = __builtin_amdgcn_mfma_f32_16x16x32_bf16(afrag, b0, acc0, 0, 0, 0);
            acc1 = __builtin_amdgcn_mfma_f32_16x16x32_bf16(afrag, b1, acc1, 0, 0, 0);
            acc2 = __builtin_amdgcn_mfma_f32_16x16x32_bf16(afrag, b2, acc2, 0, 0, 0);
            acc3 = __builtin_amdgcn_mfma_f32_16x16x32_bf16(afrag, b3, acc3, 0, 0, 0);
            accz = __builtin_amdgcn_mfma_f32_16x16x32_bf16(afrag, ones, accz, 0, 0, 0);
        }
        __syncthreads();   // LDS reuse safety before next slice restage
    }

    // z epilogue: D row m = quad*4+reg (duplicated across the 16 col-lanes)
    if (row16 == 0) {
        #pragma unroll
        for (int reg = 0; reg < 4; ++reg)
            pZ[(size_t)s * N + r * 64 + w * 16 + quad * 4 + reg] = accz[reg];
    }

    // out-tile: C/D layout col=lane&15, row=quad*4+reg
    float* outp = pAcc + ((size_t)s * N + (size_t)r * 64 + w * 16) * FOUT;
    #pragma unroll
    for (int reg = 0; reg < 4; ++reg) {
        const int row = quad * 4 + reg;
        outp[row * FOUT + ( 0 + row16)] = acc0[reg];
        outp[row * FOUT + (16 + row16)] = acc1[reg];
        outp[row * FOUT + (32 + row16)] = acc2[reg];
        outp[row * FOUT + (48 + row16)] = acc3[reg];
    }
}

// ---------------------------------------------------------------------------
// Kernel 3: out[i][f] = sum_s pAcc[s][i][f] / sum_s pZ[s][i]
// ---------------------------------------------------------------------------
__global__ __launch_bounds__(256) void k3_combine(
    const float* __restrict__ pAcc, const float* __restrict__ pZ,
    float* __restrict__ out)
{
    const int idx = blockIdx.x * 256 + threadIdx.x;
    const int i = idx >> 6;
    float num = 0.f, den = 0.f;
    #pragma unroll
    for (int s = 0; s < NSPLIT; ++s) {
        num += pAcc[(size_t)s * N * FOUT + idx];
        den += pZ[(size_t)s * N + i];
    }
    out[idx] = num / den;
}

// ---------------------------------------------------------------------------
extern "C" void kernel_launch(void* const* d_in, const int* in_sizes, int n_in,
                              void* d_out, int out_size, void* d_ws, size_t ws_size,
                              hipStream_t stream)
{
    const float* input = (const float*)d_in[0];
    const int*   adj   = (const int*)d_in[1];
    const float* W     = (const float*)d_in[2];
    const float* a     = (const float*)d_in[3];
    float* out = (float*)d_out;

    char* ws = (char*)d_ws;
    __hip_bfloat16* hbT = (__hip_bfloat16*)ws;               // 1 MB
    float* E1   = (float*)(ws + (size_t)FOUT * N * 2);       // 32 KB
    float* F1   = E1 + N;                                    // 32 KB
    float* E2   = F1 + N;                                    // 32 KB
    float* F2   = E2 + N;                                    // 32 KB
    float* pZ   = F2 + N;                                    // NSPLIT*N*4 = 256 KB
    float* pAcc = pZ + (size_t)NSPLIT * N;                   // 16.8 MB

    k1_proj<<<N / 8, 256, 0, stream>>>(input, W, a, hbT, E1, F1, E2, F2);

    dim3 g2(N / 64, NSPLIT);
    k2_attn<<<g2, 256, 0, stream>>>(adj, E1, F1, E2, F2,
                                    (const unsigned short*)hbT, pAcc, pZ);

    k3_combine<<<(N * FOUT) / 256, 256, 0, stream>>>(pAcc, pZ, out);
}

// Round 10
// 432.253 us; speedup vs baseline: 1.0698x; 1.0698x over previous
//
#include <hip/hip_runtime.h>
#include <hip/hip_bf16.h>

constexpr int N    = 8192;
constexpr int FIN  = 512;
constexpr int FOUT = 64;
constexpr int NSPLIT = 8;            // j-split across blocks -> 1024 blocks, co-resident
constexpr int JCHUNK = N / NSPLIT;   // 1024 j per block
constexpr int NSLICE = 4;            // internal slices per block
constexpr int JS     = JCHUNK / NSLICE;  // 256 j per LDS staging round
constexpr int LROW   = JS + 8;       // LDS B row pitch in bf16 (264 shorts)

typedef __attribute__((ext_vector_type(8))) short short8;
typedef __attribute__((ext_vector_type(4))) float f32x4;

union BF2U { unsigned int u; __hip_bfloat162 h; };

// ---------------------------------------------------------------------------
// Kernel 1: h = input @ W (fp32), fused epilogue:
//   E1=exp(s1), F1=exp(0.2 s1), E2=exp(s2), F2=exp(0.2 s2)  (exp-free k2)
//   + bf16 h^T write (B-operand feed for MFMA).   (unchanged from R7)
// ---------------------------------------------------------------------------
__global__ __launch_bounds__(256) void k1_proj(
    const float* __restrict__ input, const float* __restrict__ W,
    const float* __restrict__ a, __hip_bfloat16* __restrict__ hbT,
    float* __restrict__ E1, float* __restrict__ F1,
    float* __restrict__ E2, float* __restrict__ F2)
{
    __shared__ __hip_bfloat16 tile[8][64];
    const int tid  = threadIdx.x;
    const int col  = tid & 63;
    const int g    = tid >> 6;
    const int rbase = blockIdx.x * 8;

    float acc[2] = {0.f, 0.f};
    const float* in0 = input + (size_t)(rbase + g * 2) * FIN;

    for (int k = 0; k < FIN; k += 8) {
        float w[8];
        #pragma unroll
        for (int q = 0; q < 8; ++q) w[q] = W[(k + q) * FOUT + col];
        const float4 x0a = *(const float4*)(in0 + 0 * FIN + k);
        const float4 x0b = *(const float4*)(in0 + 0 * FIN + k + 4);
        const float4 x1a = *(const float4*)(in0 + 1 * FIN + k);
        const float4 x1b = *(const float4*)(in0 + 1 * FIN + k + 4);
        acc[0] = fmaf(x0a.w, w[3], fmaf(x0a.z, w[2], fmaf(x0a.y, w[1], fmaf(x0a.x, w[0], acc[0]))));
        acc[0] = fmaf(x0b.w, w[7], fmaf(x0b.z, w[6], fmaf(x0b.y, w[5], fmaf(x0b.x, w[4], acc[0]))));
        acc[1] = fmaf(x1a.w, w[3], fmaf(x1a.z, w[2], fmaf(x1a.y, w[1], fmaf(x1a.x, w[0], acc[1]))));
        acc[1] = fmaf(x1b.w, w[7], fmaf(x1b.z, w[6], fmaf(x1b.y, w[5], fmaf(x1b.x, w[4], acc[1]))));
    }

    const float a1c = a[col];
    const float a2c = a[FOUT + col];
    #pragma unroll
    for (int q = 0; q < 2; ++q) {
        float r1 = acc[q] * a1c;
        float r2 = acc[q] * a2c;
        #pragma unroll
        for (int off = 32; off >= 1; off >>= 1) {
            r1 += __shfl_xor(r1, off, 64);
            r2 += __shfl_xor(r2, off, 64);
        }
        if (col == 0) {
            const int i = rbase + g * 2 + q;
            E1[i] = __expf(r1);
            F1[i] = __expf(0.2f * r1);
            E2[i] = __expf(r2);
            F2[i] = __expf(0.2f * r2);
        }
        tile[g * 2 + q][col] = __float2bfloat16(acc[q]);
    }
    __syncthreads();

    if (tid < 128) {
        const int c = tid >> 1, part = tid & 1;
        unsigned short v[4];
        #pragma unroll
        for (int u = 0; u < 4; ++u) {
            __hip_bfloat16 hv = tile[part * 4 + u][c];
            v[u] = *reinterpret_cast<unsigned short*>(&hv);
        }
        *(ushort4*)((unsigned short*)hbT + (size_t)c * N + rbase + part * 4) =
            make_ushort4(v[0], v[1], v[2], v[3]);
    }
}

// ---------------------------------------------------------------------------
// Kernel 2: attention + PV via MFMA. R10 = R7 base + EXACTLY ONE change:
//   slice-order rotation sl = (slix + r) & 3. Concurrent near-lockstep blocks
//   then cover all 32 x 1KB windows of the 32 KB adj row pitch (vs 8 in R7)
//   -> full HBM channel coverage IF the channel-aliasing hypothesis is real.
//   (R9's register prefetch removed: it cost VGPR/occupancy and serialized
//   the post-barrier pack.)
// grid (128 r-tiles, 8 s-chunks) = 1024 blocks, ~38 KB LDS, 4 blocks/CU.
// ---------------------------------------------------------------------------
__global__ __launch_bounds__(256, 4) void k2_attn(
    const int* __restrict__ adj,
    const float* __restrict__ E1, const float* __restrict__ F1,
    const float* __restrict__ E2, const float* __restrict__ F2,
    const unsigned short* __restrict__ hbT,
    float* __restrict__ pAcc, float* __restrict__ pZ)
{
    __shared__ unsigned short Bl[64 * LROW];   // 33.8 KB, padded rows
    __shared__ unsigned int   Ml[64 * 9];      // bitmask: 8 u32/row + 1 pad word
    __shared__ float          E2l[JS];         // 1 KB
    __shared__ float          F2l[JS];         // 1 KB

    const int r   = blockIdx.x;
    const int s   = blockIdx.y;
    const int tid = threadIdx.x;
    const int w     = tid >> 6;
    const int lane  = tid & 63;
    const int row16 = lane & 15;
    const int quad  = lane >> 4;

    const int iloc = w * 16 + row16;
    const int i    = r * 64 + iloc;
    const float E1i = E1[i];
    const float F1i = F1[i];

    short8 ones;
    #pragma unroll
    for (int q = 0; q < 8; ++q) ones[q] = (short)0x3F80;   // bf16 1.0

    f32x4 acc0 = {0.f, 0.f, 0.f, 0.f};
    f32x4 acc1 = {0.f, 0.f, 0.f, 0.f};
    f32x4 acc2 = {0.f, 0.f, 0.f, 0.f};
    f32x4 acc3 = {0.f, 0.f, 0.f, 0.f};
    f32x4 accz = {0.f, 0.f, 0.f, 0.f};

    for (int slix = 0; slix < NSLICE; ++slix) {
        const int sl   = (slix + r) & (NSLICE - 1);   // R10: rotated slice order
        const int jbeg = s * JCHUNK + sl * JS;

        // ---- stage adj slice (64 rows x 1KB) and bit-pack into Ml ----
        {
            unsigned char* Mlb = (unsigned char*)Ml;   // row pitch 36 bytes
            #pragma unroll
            for (int it = 0; it < 16; ++it) {
                const int rloc = it * 4 + w;
                const int4 av = *(const int4*)(adj + (size_t)(r * 64 + rloc) * N + jbeg + lane * 4);
                unsigned int nib =
                    (av.x != 0 ? 1u : 0u) | (av.y != 0 ? 2u : 0u) |
                    (av.z != 0 ? 4u : 0u) | (av.w != 0 ? 8u : 0u);
                const unsigned int other = __shfl_xor(nib, 1, 64);
                if (!(lane & 1))
                    Mlb[rloc * 36 + (lane >> 1)] = (unsigned char)(nib | (other << 4));
            }
        }
        // ---- stage B: 64 feature rows x 256 bf16 ----
        #pragma unroll
        for (int rr = 0; rr < 8; ++rr) {
            const int seg = rr * 256 + tid;        // [0, 2048) 16B-segments
            const int f = seg >> 5, o = seg & 31;
            const short8 v = *(const short8*)((const short*)hbT + (size_t)f * N + jbeg + o * 8);
            *(short8*)(&Bl[f * LROW + o * 8]) = v;
        }
        // ---- stage E2/F2 slices (JS == 256 == blockDim) ----
        E2l[tid] = E2[jbeg + tid];
        F2l[tid] = F2[jbeg + tid];
        __syncthreads();

        #pragma unroll
        for (int it = 0; it < JS / 32; ++it) {     // 8 iterations
            const int jj = it * 32 + quad * 8;

            const unsigned int mword = Ml[iloc * 9 + it];
            const unsigned int mbyte = (mword >> (8 * quad)) & 0xffu;

            const float4 eA = *(const float4*)(&E2l[jj]);
            const float4 eB = *(const float4*)(&E2l[jj + 4]);
            const float4 fA = *(const float4*)(&F2l[jj]);
            const float4 fB = *(const float4*)(&F2l[jj + 4]);

            const short8 b0 = *(const short8*)(&Bl[(row16 +  0) * LROW + jj]);
            const short8 b1 = *(const short8*)(&Bl[(row16 + 16) * LROW + jj]);
            const short8 b2 = *(const short8*)(&Bl[(row16 + 32) * LROW + jj]);
            const short8 b3 = *(const short8*)(&Bl[(row16 + 48) * LROW + jj]);

            float e2v[8], f2v[8];
            e2v[0] = eA.x; e2v[1] = eA.y; e2v[2] = eA.z; e2v[3] = eA.w;
            e2v[4] = eB.x; e2v[5] = eB.y; e2v[6] = eB.z; e2v[7] = eB.w;
            f2v[0] = fA.x; f2v[1] = fA.y; f2v[2] = fA.z; f2v[3] = fA.w;
            f2v[4] = fB.x; f2v[5] = fB.y; f2v[6] = fB.z; f2v[7] = fB.w;

            float pv[8];
            #pragma unroll
            for (int j = 0; j < 8; ++j) {
                // exp(leakyrelu(s1+s2)) == max(E1*E2, F1*F2) exactly
                float p = fmaxf(E1i * e2v[j], F1i * f2v[j]);
                pv[j] = ((mbyte >> j) & 1u) ? p : 0.f;
            }

            short8 afrag;
            #pragma unroll
            for (int jp = 0; jp < 4; ++jp) {       // packed bf16 cvt (RNE)
                BF2U cv;
                cv.h = __float22bfloat162_rn(make_float2(pv[2 * jp], pv[2 * jp + 1]));
                afrag[2 * jp]     = (short)(cv.u & 0xffffu);
                afrag[2 * jp + 1] = (short)(cv.u >> 16);
            }

            acc0 = __builtin_amdgcn_mfma_f32_16x16x32_bf16(afrag, b0, acc0, 0, 0, 0);
            acc1 = __builtin_amdgcn_mfma_f32_16x16x32_bf16(afrag, b1, acc1, 0, 0, 0);
            acc2 = __builtin_amdgcn_mfma_f32_16x16x32_bf16(afrag, b2, acc2, 0, 0, 0);
            acc3 = __builtin_amdgcn_mfma_f32_16x16x32_bf16(afrag, b3, acc3, 0, 0, 0);
            accz = __builtin_amdgcn_mfma_f32_16x16x32_bf16(afrag, ones, accz, 0, 0, 0);
        }
        __syncthreads();   // LDS reuse safety before next slice restage
    }

    // z epilogue: D row m = quad*4+reg (duplicated across the 16 col-lanes)
    if (row16 == 0) {
        #pragma unroll
        for (int reg = 0; reg < 4; ++reg)
            pZ[(size_t)s * N + r * 64 + w * 16 + quad * 4 + reg] = accz[reg];
    }

    // out-tile: C/D layout col=lane&15, row=quad*4+reg
    float* outp = pAcc + ((size_t)s * N + (size_t)r * 64 + w * 16) * FOUT;
    #pragma unroll
    for (int reg = 0; reg < 4; ++reg) {
        const int row = quad * 4 + reg;
        outp[row * FOUT + ( 0 + row16)] = acc0[reg];
        outp[row * FOUT + (16 + row16)] = acc1[reg];
        outp[row * FOUT + (32 + row16)] = acc2[reg];
        outp[row * FOUT + (48 + row16)] = acc3[reg];
    }
}

// ---------------------------------------------------------------------------
// Kernel 3: out[i][f] = sum_s pAcc[s][i][f] / sum_s pZ[s][i]
// ---------------------------------------------------------------------------
__global__ __launch_bounds__(256) void k3_combine(
    const float* __restrict__ pAcc, const float* __restrict__ pZ,
    float* __restrict__ out)
{
    const int idx = blockIdx.x * 256 + threadIdx.x;
    const int i = idx >> 6;
    float num = 0.f, den = 0.f;
    #pragma unroll
    for (int s = 0; s < NSPLIT; ++s) {
        num += pAcc[(size_t)s * N * FOUT + idx];
        den += pZ[(size_t)s * N + i];
    }
    out[idx] = num / den;
}

// ---------------------------------------------------------------------------
extern "C" void kernel_launch(void* const* d_in, const int* in_sizes, int n_in,
                              void* d_out, int out_size, void* d_ws, size_t ws_size,
                              hipStream_t stream)
{
    const float* input = (const float*)d_in[0];
    const int*   adj   = (const int*)d_in[1];
    const float* W     = (const float*)d_in[2];
    const float* a     = (const float*)d_in[3];
    float* out = (float*)d_out;

    char* ws = (char*)d_ws;
    __hip_bfloat16* hbT = (__hip_bfloat16*)ws;               // 1 MB
    float* E1   = (float*)(ws + (size_t)FOUT * N * 2);       // 32 KB
    float* F1   = E1 + N;                                    // 32 KB
    float* E2   = F1 + N;                                    // 32 KB
    float* F2   = E2 + N;                                    // 32 KB
    float* pZ   = F2 + N;                                    // NSPLIT*N*4 = 256 KB
    float* pAcc = pZ + (size_t)NSPLIT * N;                   // 16.8 MB

    k1_proj<<<N / 8, 256, 0, stream>>>(input, W, a, hbT, E1, F1, E2, F2);

    dim3 g2(N / 64, NSPLIT);
    k2_attn<<<g2, 256, 0, stream>>>(adj, E1, F1, E2, F2,
                                    (const unsigned short*)hbT, pAcc, pZ);

    k3_combine<<<(N * FOUT) / 256, 256, 0, stream>>>(pAcc, pZ, out);
}